// Round 5
// baseline (30809.680 us; speedup 1.0000x reference)
//
#include <hip/hip_runtime.h>
#include <stdint.h>

// CORRECTNESS-ANCHOR ROUND (bisection step 2).
// Round-4 finding: NaN with the persistent-recurrence skeleton even with a
// correct-by-construction f32 xg GEMM => the persistent recur kernel (grid
// barrier / agent-scope h exchange / MFMA fragments) is the broken half.
// This round: keep gemm_naive BYTE-IDENTICAL (failure would uniquely localize
// there); replace recurrence with 512 per-step kernel launches — kernel
// boundaries are the barriers. All f32, no atomics, no MFMA, no swizzles.
//   PASS -> trusted anchor; next rounds reintroduce speed incrementally.
//   FAIL -> bug uniquely in gemm_naive / xg window / output layout.

static __device__ __forceinline__ float sigm(float x) {
  return 1.0f / (1.0f + __expf(-x));
}
static __device__ __forceinline__ float tanh_(float x) {
  float e = __expf(2.0f * x);
  return 1.0f - 2.0f / (e + 1.0f);
}

// --------------------------------------------------- naive f32 GEMM (xg tile)
// C[M][4096] f32 = A[M][1024] f32 @ B[1024][4096] f32.  M = gridDim.y*64.
// BYTE-IDENTICAL to round 4.
__global__ __launch_bounds__(256) void gemm_naive(const float* __restrict__ A,
                                                  const float* __restrict__ B,
                                                  float* __restrict__ C) {
  __shared__ float sA[64][33];
  __shared__ float sB[32][65];
  const int m0 = blockIdx.y * 64, n0 = blockIdx.x * 64;
  const int tid = threadIdx.x;
  const int ty = tid >> 4, tx = tid & 15;
  float acc[4][4] = {};
  for (int k0 = 0; k0 < 1024; k0 += 32) {
#pragma unroll
    for (int i = 0; i < 8; ++i) {  // stage A: 64 rows x 32 k
      int idx = i * 256 + tid;
      int r = idx >> 5, c = idx & 31;
      sA[r][c] = A[(size_t)(m0 + r) * 1024 + k0 + c];
    }
#pragma unroll
    for (int i = 0; i < 8; ++i) {  // stage B: 32 k x 64 n
      int idx = i * 256 + tid;
      int r = idx >> 6, c = idx & 63;
      sB[r][c] = B[(size_t)(k0 + r) * 4096 + n0 + c];
    }
    __syncthreads();
#pragma unroll 8
    for (int k = 0; k < 32; ++k)
#pragma unroll
      for (int i = 0; i < 4; ++i)
#pragma unroll
        for (int j = 0; j < 4; ++j)
          acc[i][j] += sA[ty * 4 + i][k] * sB[k][tx * 4 + j];
    __syncthreads();
  }
#pragma unroll
  for (int i = 0; i < 4; ++i)
#pragma unroll
    for (int j = 0; j < 4; ++j)
      C[(size_t)(m0 + ty * 4 + i) * 4096 + n0 + tx * 4 + j] = acc[i][j];
}

// ------------------------------------------------------------- one LSTM step
// One launch per timestep t. Block = (unit strip ub: 16 units, batch half: 32
// rows). Computes gates tile = h_{t-1}[32x1024] @ Whh[1024][4 strips x 16] in
// f32 via LDS tiling, then fuses the LSTM cell update in the epilogue.
// h ping-pongs in global f32; kernel boundary = the barrier. No atomics.
__global__ __launch_bounds__(256) void lstm_step(
    const float* __restrict__ xg,    // [W][64][4096] f32 (window-local ts)
    const float* __restrict__ whh,   // [1024][4096] f32
    const float* __restrict__ h0, const float* __restrict__ c0,
    const float* __restrict__ bias,  // [4096]
    float* __restrict__ h_buf,       // [2][64][1024] f32
    float* __restrict__ c_st,        // [64][1024] f32
    float* __restrict__ out_h,       // [512][64][1024]
    float* __restrict__ out_hT, float* __restrict__ out_cT,
    int t, int ts) {
  __shared__ float sA[32][33];       // h rows m0..+32, k slice
  __shared__ float sB[32][4][17];    // k slice x 4 gate strips x 16 units
  __shared__ float gates_s[32][68];  // 32 rows x 64 cols (gate*16+u)

  const int tid = threadIdx.x;
  const int ub = blockIdx.x;         // units ub*16 .. +16
  const int m0 = blockIdx.y * 32;    // batch rows m0 .. +32
  const float* hprev = (t == 0) ? h0 : (h_buf + (size_t)((t - 1) & 1) * 65536);

  const int ty = tid >> 4, tx = tid & 15;  // ty: 2 rows, tx: 4 cols
  float acc[2][4] = {};

  for (int k0 = 0; k0 < 1024; k0 += 32) {
#pragma unroll
    for (int i = 0; i < 4; ++i) {  // stage A: 32 rows x 32 k
      int idx = i * 256 + tid;
      int r = idx >> 5, c = idx & 31;
      sA[r][c] = hprev[(size_t)(m0 + r) * 1024 + k0 + c];
    }
#pragma unroll
    for (int i = 0; i < 8; ++i) {  // stage B: 32 k x (4 gates x 16 units)
      int idx = i * 256 + tid;
      int r = idx >> 6, cc = idx & 63;
      sB[r][cc >> 4][cc & 15] =
          whh[(size_t)(k0 + r) * 4096 + (cc >> 4) * 1024 + ub * 16 + (cc & 15)];
    }
    __syncthreads();
#pragma unroll 8
    for (int k = 0; k < 32; ++k)
#pragma unroll
      for (int i = 0; i < 2; ++i)
#pragma unroll
        for (int j = 0; j < 4; ++j)
          acc[i][j] += sA[ty * 2 + i][k] * sB[k][tx >> 2][(tx & 3) * 4 + j];
    __syncthreads();
  }

#pragma unroll
  for (int i = 0; i < 2; ++i)
#pragma unroll
    for (int j = 0; j < 4; ++j)
      gates_s[ty * 2 + i][tx * 4 + j] = acc[i][j];
  __syncthreads();

  // cell update: 32x16 = 512 (row,unit) pairs, 2 per thread; exclusive owner.
#pragma unroll
  for (int pi = 0; pi < 2; ++pi) {
    int p = pi * 256 + tid;
    int bl = p >> 4, u = p & 15;
    int b = m0 + bl;
    int unit = ub * 16 + u;
    const float* xgp = xg + ((size_t)ts * 64 + b) * 4096 + unit;
    float r0 = gates_s[bl][u]      + xgp[0]    + bias[unit];
    float r1 = gates_s[bl][16 + u] + xgp[1024] + bias[1024 + unit];
    float r2 = gates_s[bl][32 + u] + xgp[2048] + bias[2048 + unit];
    float r3 = gates_s[bl][48 + u] + xgp[3072] + bias[3072 + unit];
    float ig = sigm(r0);
    float fg = sigm(r1);
    float gg = tanh_(r2);
    float og = sigm(r3);
    float c_old = (t == 0) ? c0[b * 1024 + unit] : c_st[b * 1024 + unit];
    float c_new = fg * c_old + ig * gg;
    float h_new = og * tanh_(c_new);
    c_st[b * 1024 + unit] = c_new;
    h_buf[(size_t)(t & 1) * 65536 + (size_t)b * 1024 + unit] = h_new;
    out_h[(size_t)t * 65536 + (size_t)b * 1024 + unit] = h_new;
    if (t == 511) {
      out_hT[b * 1024 + unit] = h_new;
      out_cT[b * 1024 + unit] = c_new;
    }
  }
}

// -------------------------------------------------------------------- launch
extern "C" void kernel_launch(void* const* d_in, const int* in_sizes, int n_in,
                              void* d_out, int out_size, void* d_ws, size_t ws_size,
                              hipStream_t stream) {
  const float* x = (const float*)d_in[0];
  const float* h0 = (const float*)d_in[1];
  const float* c0 = (const float*)d_in[2];
  const float* wih = (const float*)d_in[3];
  const float* whh = (const float*)d_in[4];
  const float* bias = (const float*)d_in[5];

  float* out = (float*)d_out;
  float* out_h = out;                              // [512][64][1024]
  float* out_hT = out + (size_t)512 * 64 * 1024;   // [64][1024]
  float* out_cT = out_hT + 64 * 1024;              // [64][1024]

  // adaptive xg window W (steps): 16 -> 8 -> 4, so workspace always fits
  const size_t fixed = (size_t)2 * 64 * 1024 * 4   // h_buf ping-pong
                       + (size_t)64 * 1024 * 4;    // c_state
  int W = 16;
  while (W > 4 && fixed + (size_t)W * 64 * 4096 * 4 > ws_size) W >>= 1;

  char* ws = (char*)d_ws;
  float* xg = (float*)ws;     ws += (size_t)W * 64 * 4096 * 4;  // <=16.8MB
  float* h_buf = (float*)ws;  ws += (size_t)2 * 64 * 1024 * 4;  // 512KB
  float* c_st = (float*)ws;                                     // 256KB

  for (int t0 = 0; t0 < 512; t0 += W) {
    gemm_naive<<<dim3(64, W), 256, 0, stream>>>(x + (size_t)t0 * 64 * 1024, wih, xg);
    for (int ts = 0; ts < W; ++ts)
      lstm_step<<<dim3(64, 2), 256, 0, stream>>>(xg, whh, h0, c0, bias, h_buf, c_st,
                                                 out_h, out_hT, out_cT, t0 + ts, ts);
  }
}

// Round 6
// 6351.580 us; speedup vs baseline: 4.8507x; 4.8507x over previous
//
#include <hip/hip_runtime.h>
#include <stdint.h>

// Trusted skeleton (round-5 anchor): per-step kernel launches, kernel boundary
// = barrier, exclusive (b,unit) ownership, f32 cell state, no atomics, no grid
// barrier, no global_load_lds. This round: MFMA compute inside the skeleton.
//   gemm_xg: bf16 MFMA 128x128 (m97 fragment layout), bias folded in epilogue.
//   lstm_step_mfma: wave==gate, one 16x16x32-MFMA chain over K=1024; h kept as
//   bf16 ping-pong (A-fragments load directly); h0/c0 pre-staged once.

typedef unsigned short u16;
typedef __attribute__((ext_vector_type(8))) short bf16x8;
typedef __attribute__((ext_vector_type(4))) float f32x4;

static __device__ __forceinline__ u16 f2b(float f) {
  uint32_t b = __float_as_uint(f);
  return (u16)((b + 0x7fffu + ((b >> 16) & 1u)) >> 16);  // RNE
}
static __device__ __forceinline__ uint64_t pack4(float4 v) {
  return (uint64_t)f2b(v.x) | ((uint64_t)f2b(v.y) << 16) |
         ((uint64_t)f2b(v.z) << 32) | ((uint64_t)f2b(v.w) << 48);
}
static __device__ __forceinline__ float sigm(float x) {
  return 1.0f / (1.0f + __expf(-x));
}
static __device__ __forceinline__ float tanh_(float x) {
  float e = __expf(2.0f * x);
  return 1.0f - 2.0f / (e + 1.0f);
}

// ---------------------------------------------------------------- prep kernels
// W [1024][4096] f32 -> W^T [4096][1024] bf16 (W_ih and W_hh via blockIdx.z)
__global__ __launch_bounds__(256) void transpose_w(const float* __restrict__ Wih,
                                                   const float* __restrict__ Whh,
                                                   u16* __restrict__ Tih,
                                                   u16* __restrict__ Thh) {
  __shared__ float tile[64][65];
  const float* src = blockIdx.z ? Whh : Wih;
  u16* dst = blockIdx.z ? Thh : Tih;
  int k0 = blockIdx.y * 64, n0 = blockIdx.x * 64;
  int tid = threadIdx.x;
#pragma unroll
  for (int i = 0; i < 16; ++i) {
    int idx = i * 256 + tid;
    int kl = idx >> 6, nl = idx & 63;
    tile[kl][nl] = src[(size_t)(k0 + kl) * 4096 + n0 + nl];
  }
  __syncthreads();
#pragma unroll
  for (int i = 0; i < 16; ++i) {
    int idx = i * 256 + tid;
    int nl = idx >> 6, kl = idx & 63;
    dst[(size_t)(n0 + nl) * 1024 + k0 + kl] = f2b(tile[kl][nl]);
  }
}

// h0 [64][1024] f32 -> h_buf[1] bf16
__global__ __launch_bounds__(256) void convert_h0(const float* __restrict__ h0,
                                                  u16* __restrict__ dst) {
  int i = blockIdx.x * 256 + threadIdx.x;  // 16384 float4s
  float4 v = ((const float4*)h0)[i];
  ((uint64_t*)dst)[i] = pack4(v);
}

// ------------------------------------------------------------------- big GEMM
// C[M][4096] f32 = A[M][1024] f32 @ Bt[4096][1024]^T + bias.  M = gridDim.y*128.
// m97 fragment layout; A and B reg-staged into LDS (no global_load_lds).
__global__ __launch_bounds__(256) void gemm_xg(const float* __restrict__ A,
                                               const u16* __restrict__ Bt,
                                               const float* __restrict__ bias,
                                               float* __restrict__ C) {
  __shared__ u16 sA[2][128 * 32];
  __shared__ u16 sB[2][128 * 32];
  const int tid = threadIdx.x;
  const int wave = tid >> 6, lane = tid & 63;
  const int bx = blockIdx.x, by = blockIdx.y;
  const int wr = wave >> 1, wc = wave & 1;  // wave computes 64x64
  const int lm = lane & 15, ko = (lane >> 4) * 8;

  // A reg-stage: row ar (0..31) within wave quarter, col base ac (0 or 16)
  const int ar = lane >> 1, ac = (lane & 1) * 16;
  const float* gA = A + (size_t)(by * 128 + wave * 32 + ar) * 1024 + ac;
  // B reg-stage: row br (0..15) pair, col base (lane&3)*8
  const u16* gB = Bt + (size_t)(bx * 128 + wave * 32 + (lane >> 2)) * 1024 + (lane & 3) * 8;
  const int bidx = wave * 1024 + (lane >> 2) * 32 + (lane & 3) * 8;

  f32x4 acc[4][4] = {};

  auto stage = [&](int kt, int buf) {
    const u16* gb = gB + kt * 32;
    bf16x8 b0 = *(const bf16x8*)gb;
    bf16x8 b1 = *(const bf16x8*)(gb + 16 * 1024);
    *(bf16x8*)&sB[buf][bidx] = b0;
    *(bf16x8*)&sB[buf][bidx + 512] = b1;
    const float* ga = gA + kt * 32;
    float4 v0 = *(const float4*)(ga + 0);
    float4 v1 = *(const float4*)(ga + 4);
    float4 v2 = *(const float4*)(ga + 8);
    float4 v3 = *(const float4*)(ga + 12);
    uint64_t* la = (uint64_t*)&sA[buf][wave * 1024 + ar * 32 + ac];
    la[0] = pack4(v0);
    la[1] = pack4(v1);
    la[2] = pack4(v2);
    la[3] = pack4(v3);
  };

  stage(0, 0);
  __syncthreads();
  int p = 0;
  for (int kt = 0; kt < 32; ++kt) {
    if (kt < 31) stage(kt + 1, p ^ 1);
    bf16x8 af[4], bfv[4];
#pragma unroll
    for (int i = 0; i < 4; ++i)
      af[i] = *(const bf16x8*)&sA[p][(wr * 64 + i * 16 + lm) * 32 + ko];
#pragma unroll
    for (int j = 0; j < 4; ++j)
      bfv[j] = *(const bf16x8*)&sB[p][(wc * 64 + j * 16 + lm) * 32 + ko];
#pragma unroll
    for (int i = 0; i < 4; ++i)
#pragma unroll
      for (int j = 0; j < 4; ++j)
        acc[i][j] = __builtin_amdgcn_mfma_f32_16x16x32_bf16(af[i], bfv[j], acc[i][j], 0, 0, 0);
    __syncthreads();
    p ^= 1;
  }

  float bj[4];
#pragma unroll
  for (int j = 0; j < 4; ++j)
    bj[j] = bias[bx * 128 + wc * 64 + j * 16 + lm];
#pragma unroll
  for (int i = 0; i < 4; ++i) {
    int row = by * 128 + wr * 64 + i * 16 + (lane >> 4) * 4;
#pragma unroll
    for (int j = 0; j < 4; ++j) {
      int col = bx * 128 + wc * 64 + j * 16 + lm;
#pragma unroll
      for (int r = 0; r < 4; ++r)
        C[(size_t)(row + r) * 4096 + col] = acc[i][j][r] + bj[j];
    }
  }
}

// ------------------------------------------------------------- one LSTM step
// One launch per timestep. Grid (64 unit-strips, 4 batch-quarters), block 256.
// Wave w computes gate w's 16x16 tile: full K=1024 MFMA chain, A-frags loaded
// directly from bf16 h ping-pong, B-frags from whh_t. 4KB LDS handoff, then
// each thread owns exactly one (b, unit): cell update + stores.
__global__ __launch_bounds__(256, 1) void lstm_step_mfma(
    const float* __restrict__ xg,    // [W][64][4096] f32, bias already added
    const u16* __restrict__ whh_t,   // [4096][1024] bf16
    u16* __restrict__ h_buf,         // [2][64][1024] bf16 ping-pong
    float* __restrict__ c_st,        // [64][1024] f32
    float* __restrict__ out_h,       // [512][64][1024] f32
    float* __restrict__ out_hT, float* __restrict__ out_cT,
    int t, int ts) {
  __shared__ float xchg[4][16][16];

  const int tid = threadIdx.x;
  const int wave = tid >> 6, lane = tid & 63;  // wave == gate
  const int ub = blockIdx.x;                   // units ub*16 .. +16
  const int bq = blockIdx.y;                   // batch rows bq*16 .. +16

  const u16* hprev = h_buf + (size_t)((t - 1) & 1) * 65536;
  // B-frag: n = wave*1024 + ub*16 + (lane&15), k = (lane>>4)*8 + j + 32*kk
  const u16* bp =
      whh_t + (size_t)(wave * 1024 + ub * 16 + (lane & 15)) * 1024 + (lane >> 4) * 8;
  // A-frag: m = bq*16 + (lane&15), same k pattern
  const u16* ap = hprev + (size_t)(bq * 16 + (lane & 15)) * 1024 + (lane >> 4) * 8;

  f32x4 acc = {0.f, 0.f, 0.f, 0.f};
#pragma unroll
  for (int kk = 0; kk < 32; ++kk) {
    bf16x8 b = *(const bf16x8*)(bp + kk * 32);
    bf16x8 a = *(const bf16x8*)(ap + kk * 32);
    acc = __builtin_amdgcn_mfma_f32_16x16x32_bf16(a, b, acc, 0, 0, 0);
  }
  {
    int crow = (lane >> 4) * 4, ccol = lane & 15;  // C: col=lane&15, row=(lane>>4)*4+r
#pragma unroll
    for (int r = 0; r < 4; ++r) xchg[wave][crow + r][ccol] = acc[r];
  }
  __syncthreads();

  const int r_b = tid >> 4, u = tid & 15;
  const int b = bq * 16 + r_b;
  const int unit = ub * 16 + u;
  const float* xgp = xg + ((size_t)ts * 64 + b) * 4096 + unit;
  float r0 = xchg[0][r_b][u] + xgp[0];
  float r1 = xchg[1][r_b][u] + xgp[1024];
  float r2 = xchg[2][r_b][u] + xgp[2048];
  float r3 = xchg[3][r_b][u] + xgp[3072];
  float ig = sigm(r0), fg = sigm(r1), gg = tanh_(r2), og = sigm(r3);
  float c_new = fg * c_st[b * 1024 + unit] + ig * gg;
  float h_new = og * tanh_(c_new);
  c_st[b * 1024 + unit] = c_new;
  h_buf[(size_t)(t & 1) * 65536 + (size_t)b * 1024 + unit] = f2b(h_new);
  out_h[(size_t)t * 65536 + (size_t)b * 1024 + unit] = h_new;
  if (t == 511) {
    out_hT[b * 1024 + unit] = h_new;
    out_cT[b * 1024 + unit] = c_new;
  }
}

// -------------------------------------------------------------------- launch
extern "C" void kernel_launch(void* const* d_in, const int* in_sizes, int n_in,
                              void* d_out, int out_size, void* d_ws, size_t ws_size,
                              hipStream_t stream) {
  const float* x = (const float*)d_in[0];
  const float* h0 = (const float*)d_in[1];
  const float* c0 = (const float*)d_in[2];
  const float* wih = (const float*)d_in[3];
  const float* whh = (const float*)d_in[4];
  const float* bias = (const float*)d_in[5];

  float* out = (float*)d_out;
  float* out_h = out;                              // [512][64][1024]
  float* out_hT = out + (size_t)512 * 64 * 1024;   // [64][1024]
  float* out_cT = out_hT + 64 * 1024;              // [64][1024]

  // adaptive xg window (f32): W in {16,8,4,2}
  const size_t fixed = (size_t)2 * 4096 * 1024 * 2   // wih_t + whh_t
                       + (size_t)2 * 64 * 1024 * 2   // h_buf bf16 ping-pong
                       + (size_t)64 * 1024 * 4;      // c_state
  int W = 16;
  while (W > 2 && fixed + (size_t)W * 64 * 4096 * 4 > ws_size) W >>= 1;

  char* ws = (char*)d_ws;
  u16* wih_t = (u16*)ws;      ws += (size_t)4096 * 1024 * 2;    // 8MB
  u16* whh_t = (u16*)ws;      ws += (size_t)4096 * 1024 * 2;    // 8MB
  float* xg = (float*)ws;     ws += (size_t)W * 64 * 4096 * 4;  // <=16.8MB
  u16* h_buf = (u16*)ws;      ws += (size_t)2 * 64 * 1024 * 2;  // 256KB
  float* c_st = (float*)ws;                                     // 256KB

  convert_h0<<<64, 256, 0, stream>>>(h0, h_buf + 65536);  // h_{-1} lives in buf 1
  hipMemcpyAsync(c_st, c0, (size_t)64 * 1024 * 4, hipMemcpyDeviceToDevice, stream);
  transpose_w<<<dim3(64, 16, 2), 256, 0, stream>>>(wih, whh, wih_t, whh_t);

  for (int t0 = 0; t0 < 512; t0 += W) {
    gemm_xg<<<dim3(32, W / 2), 256, 0, stream>>>(x + (size_t)t0 * 64 * 1024, wih_t, bias, xg);
    for (int ts = 0; ts < W; ++ts)
      lstm_step_mfma<<<dim3(64, 4), 256, 0, stream>>>(xg, whh_t, h_buf, c_st, out_h,
                                                      out_hT, out_cT, t0 + ts, ts);
  }
}

// Round 7
// 6337.133 us; speedup vs baseline: 4.8618x; 1.0023x over previous
//
#include <hip/hip_runtime.h>
#include <stdint.h>

// Trusted skeleton (round-5/6): per-step kernel launches, kernel boundary =
// barrier, exclusive (b,unit) ownership, f32 cell state, no atomics, no grid
// barrier, no global_load_lds.
// Round-7 change (single structural change vs round 6): K-split step kernel —
// 512 threads/block, 8 waves = (gate, K-half), each wave 2 independent 8-deep
// MFMA chains (was 1 wave/SIMD with one 32-deep chain). 2 waves/SIMD TLP +
// 2-chain ILP to hide MFMA+L2 latency; xg/c loads hoisted above the chain.

typedef unsigned short u16;
typedef __attribute__((ext_vector_type(8))) short bf16x8;
typedef __attribute__((ext_vector_type(4))) float f32x4;

static __device__ __forceinline__ u16 f2b(float f) {
  uint32_t b = __float_as_uint(f);
  return (u16)((b + 0x7fffu + ((b >> 16) & 1u)) >> 16);  // RNE
}
static __device__ __forceinline__ uint64_t pack4(float4 v) {
  return (uint64_t)f2b(v.x) | ((uint64_t)f2b(v.y) << 16) |
         ((uint64_t)f2b(v.z) << 32) | ((uint64_t)f2b(v.w) << 48);
}
static __device__ __forceinline__ float sigm(float x) {
  return 1.0f / (1.0f + __expf(-x));
}
static __device__ __forceinline__ float tanh_(float x) {
  float e = __expf(2.0f * x);
  return 1.0f - 2.0f / (e + 1.0f);
}

// ---------------------------------------------------------------- prep kernels
// W [1024][4096] f32 -> W^T [4096][1024] bf16 (W_ih and W_hh via blockIdx.z)
__global__ __launch_bounds__(256) void transpose_w(const float* __restrict__ Wih,
                                                   const float* __restrict__ Whh,
                                                   u16* __restrict__ Tih,
                                                   u16* __restrict__ Thh) {
  __shared__ float tile[64][65];
  const float* src = blockIdx.z ? Whh : Wih;
  u16* dst = blockIdx.z ? Thh : Tih;
  int k0 = blockIdx.y * 64, n0 = blockIdx.x * 64;
  int tid = threadIdx.x;
#pragma unroll
  for (int i = 0; i < 16; ++i) {
    int idx = i * 256 + tid;
    int kl = idx >> 6, nl = idx & 63;
    tile[kl][nl] = src[(size_t)(k0 + kl) * 4096 + n0 + nl];
  }
  __syncthreads();
#pragma unroll
  for (int i = 0; i < 16; ++i) {
    int idx = i * 256 + tid;
    int nl = idx >> 6, kl = idx & 63;
    dst[(size_t)(n0 + nl) * 1024 + k0 + kl] = f2b(tile[kl][nl]);
  }
}

// h0 [64][1024] f32 -> h_buf[1] bf16
__global__ __launch_bounds__(256) void convert_h0(const float* __restrict__ h0,
                                                  u16* __restrict__ dst) {
  int i = blockIdx.x * 256 + threadIdx.x;  // 16384 float4s
  float4 v = ((const float4*)h0)[i];
  ((uint64_t*)dst)[i] = pack4(v);
}

// ------------------------------------------------------------------- big GEMM
// C[M][4096] f32 = A[M][1024] f32 @ Bt[4096][1024]^T + bias.  M = gridDim.y*128.
// m97 fragment layout; A and B reg-staged into LDS. (unchanged from round 6)
__global__ __launch_bounds__(256) void gemm_xg(const float* __restrict__ A,
                                               const u16* __restrict__ Bt,
                                               const float* __restrict__ bias,
                                               float* __restrict__ C) {
  __shared__ u16 sA[2][128 * 32];
  __shared__ u16 sB[2][128 * 32];
  const int tid = threadIdx.x;
  const int wave = tid >> 6, lane = tid & 63;
  const int bx = blockIdx.x, by = blockIdx.y;
  const int wr = wave >> 1, wc = wave & 1;  // wave computes 64x64
  const int lm = lane & 15, ko = (lane >> 4) * 8;

  const int ar = lane >> 1, ac = (lane & 1) * 16;
  const float* gA = A + (size_t)(by * 128 + wave * 32 + ar) * 1024 + ac;
  const u16* gB = Bt + (size_t)(bx * 128 + wave * 32 + (lane >> 2)) * 1024 + (lane & 3) * 8;
  const int bidx = wave * 1024 + (lane >> 2) * 32 + (lane & 3) * 8;

  f32x4 acc[4][4] = {};

  auto stage = [&](int kt, int buf) {
    const u16* gb = gB + kt * 32;
    bf16x8 b0 = *(const bf16x8*)gb;
    bf16x8 b1 = *(const bf16x8*)(gb + 16 * 1024);
    *(bf16x8*)&sB[buf][bidx] = b0;
    *(bf16x8*)&sB[buf][bidx + 512] = b1;
    const float* ga = gA + kt * 32;
    float4 v0 = *(const float4*)(ga + 0);
    float4 v1 = *(const float4*)(ga + 4);
    float4 v2 = *(const float4*)(ga + 8);
    float4 v3 = *(const float4*)(ga + 12);
    uint64_t* la = (uint64_t*)&sA[buf][wave * 1024 + ar * 32 + ac];
    la[0] = pack4(v0);
    la[1] = pack4(v1);
    la[2] = pack4(v2);
    la[3] = pack4(v3);
  };

  stage(0, 0);
  __syncthreads();
  int p = 0;
  for (int kt = 0; kt < 32; ++kt) {
    if (kt < 31) stage(kt + 1, p ^ 1);
    bf16x8 af[4], bfv[4];
#pragma unroll
    for (int i = 0; i < 4; ++i)
      af[i] = *(const bf16x8*)&sA[p][(wr * 64 + i * 16 + lm) * 32 + ko];
#pragma unroll
    for (int j = 0; j < 4; ++j)
      bfv[j] = *(const bf16x8*)&sB[p][(wc * 64 + j * 16 + lm) * 32 + ko];
#pragma unroll
    for (int i = 0; i < 4; ++i)
#pragma unroll
      for (int j = 0; j < 4; ++j)
        acc[i][j] = __builtin_amdgcn_mfma_f32_16x16x32_bf16(af[i], bfv[j], acc[i][j], 0, 0, 0);
    __syncthreads();
    p ^= 1;
  }

  float bj[4];
#pragma unroll
  for (int j = 0; j < 4; ++j)
    bj[j] = bias[bx * 128 + wc * 64 + j * 16 + lm];
#pragma unroll
  for (int i = 0; i < 4; ++i) {
    int row = by * 128 + wr * 64 + i * 16 + (lane >> 4) * 4;
#pragma unroll
    for (int j = 0; j < 4; ++j) {
      int col = bx * 128 + wc * 64 + j * 16 + lm;
#pragma unroll
      for (int r = 0; r < 4; ++r)
        C[(size_t)(row + r) * 4096 + col] = acc[i][j][r] + bj[j];
    }
  }
}

// ------------------------------------------------------------- one LSTM step
// One launch per timestep. Grid (64 unit-strips, 4 batch-quarters), block 512
// (8 waves). Wave w = (gate = w&3, K-half = w>>2): 16x16 tile over K=512 as
// TWO independent 8-deep MFMA chains. 8KB LDS reduce, then tid<256 each owns
// one (b, unit): cell update + stores. xg/c loads hoisted above the chain.
__global__ __launch_bounds__(512, 1) void lstm_step_mfma(
    const float* __restrict__ xg,    // [W][64][4096] f32, bias already added
    const u16* __restrict__ whh_t,   // [4096][1024] bf16
    u16* __restrict__ h_buf,         // [2][64][1024] bf16 ping-pong
    float* __restrict__ c_st,        // [64][1024] f32
    float* __restrict__ out_h,       // [512][64][1024] f32
    float* __restrict__ out_hT, float* __restrict__ out_cT,
    int t, int ts) {
  __shared__ float xchg[8][16][16];

  const int tid = threadIdx.x;
  const int wave = tid >> 6, lane = tid & 63;
  const int gate = wave & 3, kh = wave >> 2;
  const int ub = blockIdx.x;  // units ub*16 .. +16
  const int bq = blockIdx.y;  // batch rows bq*16 .. +16

  // hoisted epilogue loads (waves 0-3 only; overlap the MFMA chain)
  const int r_b = tid >> 4, u = tid & 15;
  const int b = bq * 16 + r_b;
  const int unit = ub * 16 + u;
  float xr0, xr1, xr2, xr3, c_old;
  if (tid < 256) {
    const float* xgp = xg + ((size_t)ts * 64 + b) * 4096 + unit;
    xr0 = xgp[0];
    xr1 = xgp[1024];
    xr2 = xgp[2048];
    xr3 = xgp[3072];
    c_old = c_st[b * 1024 + unit];
  }

  const u16* hprev = h_buf + (size_t)((t - 1) & 1) * 65536;
  // B-frag: n = gate*1024 + ub*16 + (lane&15); k = kh*512 + chunk*32 + (lane>>4)*8 + j
  const u16* bp = whh_t + (size_t)(gate * 1024 + ub * 16 + (lane & 15)) * 1024 +
                  kh * 512 + (lane >> 4) * 8;
  // A-frag: m = bq*16 + (lane&15), same k pattern
  const u16* ap = hprev + (size_t)(bq * 16 + (lane & 15)) * 1024 + kh * 512 + (lane >> 4) * 8;

  f32x4 acc0 = {0.f, 0.f, 0.f, 0.f}, acc1 = acc0;
#pragma unroll
  for (int kk = 0; kk < 8; ++kk) {
    bf16x8 b0 = *(const bf16x8*)(bp + kk * 64);
    bf16x8 a0 = *(const bf16x8*)(ap + kk * 64);
    bf16x8 b1 = *(const bf16x8*)(bp + kk * 64 + 32);
    bf16x8 a1 = *(const bf16x8*)(ap + kk * 64 + 32);
    acc0 = __builtin_amdgcn_mfma_f32_16x16x32_bf16(a0, b0, acc0, 0, 0, 0);
    acc1 = __builtin_amdgcn_mfma_f32_16x16x32_bf16(a1, b1, acc1, 0, 0, 0);
  }
  f32x4 acc = acc0 + acc1;
  {
    int crow = (lane >> 4) * 4, ccol = lane & 15;  // C: col=lane&15, row=(lane>>4)*4+r
#pragma unroll
    for (int r = 0; r < 4; ++r) xchg[wave][crow + r][ccol] = acc[r];
  }
  __syncthreads();

  if (tid < 256) {
    float r0 = xchg[0][r_b][u] + xchg[4][r_b][u] + xr0;
    float r1 = xchg[1][r_b][u] + xchg[5][r_b][u] + xr1;
    float r2 = xchg[2][r_b][u] + xchg[6][r_b][u] + xr2;
    float r3 = xchg[3][r_b][u] + xchg[7][r_b][u] + xr3;
    float ig = sigm(r0), fg = sigm(r1), gg = tanh_(r2), og = sigm(r3);
    float c_new = fg * c_old + ig * gg;
    float h_new = og * tanh_(c_new);
    c_st[b * 1024 + unit] = c_new;
    h_buf[(size_t)(t & 1) * 65536 + (size_t)b * 1024 + unit] = f2b(h_new);
    out_h[(size_t)t * 65536 + (size_t)b * 1024 + unit] = h_new;
    if (t == 511) {
      out_hT[b * 1024 + unit] = h_new;
      out_cT[b * 1024 + unit] = c_new;
    }
  }
}

// -------------------------------------------------------------------- launch
extern "C" void kernel_launch(void* const* d_in, const int* in_sizes, int n_in,
                              void* d_out, int out_size, void* d_ws, size_t ws_size,
                              hipStream_t stream) {
  const float* x = (const float*)d_in[0];
  const float* h0 = (const float*)d_in[1];
  const float* c0 = (const float*)d_in[2];
  const float* wih = (const float*)d_in[3];
  const float* whh = (const float*)d_in[4];
  const float* bias = (const float*)d_in[5];

  float* out = (float*)d_out;
  float* out_h = out;                              // [512][64][1024]
  float* out_hT = out + (size_t)512 * 64 * 1024;   // [64][1024]
  float* out_cT = out_hT + 64 * 1024;              // [64][1024]

  // adaptive xg window (f32): W in {16,8,4,2}
  const size_t fixed = (size_t)2 * 4096 * 1024 * 2   // wih_t + whh_t
                       + (size_t)2 * 64 * 1024 * 2   // h_buf bf16 ping-pong
                       + (size_t)64 * 1024 * 4;      // c_state
  int W = 16;
  while (W > 2 && fixed + (size_t)W * 64 * 4096 * 4 > ws_size) W >>= 1;

  char* ws = (char*)d_ws;
  u16* wih_t = (u16*)ws;      ws += (size_t)4096 * 1024 * 2;    // 8MB
  u16* whh_t = (u16*)ws;      ws += (size_t)4096 * 1024 * 2;    // 8MB
  float* xg = (float*)ws;     ws += (size_t)W * 64 * 4096 * 4;  // <=16.8MB
  u16* h_buf = (u16*)ws;      ws += (size_t)2 * 64 * 1024 * 2;  // 256KB
  float* c_st = (float*)ws;                                     // 256KB

  convert_h0<<<64, 256, 0, stream>>>(h0, h_buf + 65536);  // h_{-1} lives in buf 1
  hipMemcpyAsync(c_st, c0, (size_t)64 * 1024 * 4, hipMemcpyDeviceToDevice, stream);
  transpose_w<<<dim3(64, 16, 2), 256, 0, stream>>>(wih, whh, wih_t, whh_t);

  for (int t0 = 0; t0 < 512; t0 += W) {
    gemm_xg<<<dim3(32, W / 2), 256, 0, stream>>>(x + (size_t)t0 * 64 * 1024, wih_t, bias, xg);
    for (int ts = 0; ts < W; ++ts)
      lstm_step_mfma<<<dim3(64, 4), 512, 0, stream>>>(xg, whh_t, h_buf, c_st, out_h,
                                                      out_hT, out_cT, t0 + ts, ts);
  }
}